// Round 1
// baseline (208.187 us; speedup 1.0000x reference)
//
#include <hip/hip_runtime.h>

// HingeLoss: B=4M rows, 7 classes.
// elem = mask ? |logit - target| : relu(logit - target); out = sum(elem)
// mask[i][j] = j in repr_num[i][0..2];  target = (label==1) ? 1 : 0

#define NUM_CLASSES 7

__global__ __launch_bounds__(256) void hinge_sum_kernel(
    const float* __restrict__ logit,      // [B,7] f32
    const int* __restrict__ label,        // [B]   i32
    const int* __restrict__ repr_num,     // [B,3] ints (harness uploads integer as i32)
    float* __restrict__ out,              // [1]   f32
    int B)
{
    int tid = blockIdx.x * blockDim.x + threadIdx.x;
    int stride = gridDim.x * blockDim.x;

    float acc = 0.0f;
    for (int i = tid; i < B; i += stride) {
        // membership bitmask over 7 classes
        int r0 = repr_num[3 * i + 0];
        int r1 = repr_num[3 * i + 1];
        int r2 = repr_num[3 * i + 2];
        unsigned mbits = (1u << r0) | (1u << r1) | (1u << r2);

        float target = (label[i] == 1) ? 1.0f : 0.0f;

        const float* lrow = logit + (size_t)i * NUM_CLASSES;
        #pragma unroll
        for (int j = 0; j < NUM_CLASSES; ++j) {
            float d = lrow[j] - target;
            float v = ((mbits >> j) & 1u) ? fabsf(d) : fmaxf(d, 0.0f);
            acc += v;
        }
    }

    // wave (64-lane) butterfly reduce
    #pragma unroll
    for (int off = 32; off > 0; off >>= 1)
        acc += __shfl_down(acc, off, 64);

    __shared__ float wave_sums[4];  // 256 threads / 64 lanes
    int lane = threadIdx.x & 63;
    int wid  = threadIdx.x >> 6;
    if (lane == 0) wave_sums[wid] = acc;
    __syncthreads();

    if (threadIdx.x == 0) {
        float s = wave_sums[0] + wave_sums[1] + wave_sums[2] + wave_sums[3];
        atomicAdd(out, s);  // device-scope by default on CDNA
    }
}

extern "C" void kernel_launch(void* const* d_in, const int* in_sizes, int n_in,
                              void* d_out, int out_size, void* d_ws, size_t ws_size,
                              hipStream_t stream) {
    const float* logit    = (const float*)d_in[0];
    const int*   label    = (const int*)d_in[1];
    const int*   repr_num = (const int*)d_in[2];
    float*       out      = (float*)d_out;

    int B = in_sizes[1];  // label is [B]

    // d_out is re-poisoned to 0xAA before every timed launch — zero it here.
    hipMemsetAsync(out, 0, sizeof(float), stream);

    // memory-bound: cap grid at ~8 blocks/CU and grid-stride (Guideline 11)
    int threads = 256;
    int blocks  = 2048;
    hinge_sum_kernel<<<blocks, threads, 0, stream>>>(logit, label, repr_num, out, B);
}

// Round 2
// 206.572 us; speedup vs baseline: 1.0078x; 1.0078x over previous
//
#include <hip/hip_runtime.h>

// HingeLoss: B=4M rows, 7 classes.
// elem = mask ? |logit - target| : relu(logit - target); out = sum(elem)
// mask[i][j] = (j in repr_num[i][0..2]);  target = (label==1) ? 1 : 0
//
// Vectorized: 4 rows per thread -> 7x float4 logit loads, 1x int4 label,
// 3x int4 repr. All global loads are 16B/lane unit-stride (dwordx4).

#define NUM_CLASSES 7

__global__ __launch_bounds__(256) void hinge_sum_kernel(
    const float4* __restrict__ logit4,    // [B*7/4] = [7*nchunk]
    const int4* __restrict__ label4,      // [B/4]
    const int4* __restrict__ repr4,       // [B*3/4] = [3*nchunk]
    float* __restrict__ out,              // [1] f32
    int nchunk)                           // B/4
{
    int tid = blockIdx.x * blockDim.x + threadIdx.x;
    int stride = gridDim.x * blockDim.x;

    float acc = 0.0f;
    for (int t = tid; t < nchunk; t += stride) {
        // 28 logits covering rows 4t..4t+3
        float4 L0 = logit4[7 * (size_t)t + 0];
        float4 L1 = logit4[7 * (size_t)t + 1];
        float4 L2 = logit4[7 * (size_t)t + 2];
        float4 L3 = logit4[7 * (size_t)t + 3];
        float4 L4 = logit4[7 * (size_t)t + 4];
        float4 L5 = logit4[7 * (size_t)t + 5];
        float4 L6 = logit4[7 * (size_t)t + 6];

        int4 lab = label4[t];

        int4 r0 = repr4[3 * (size_t)t + 0];  // {row0.a,row0.b,row0.c,row1.a}
        int4 r1 = repr4[3 * (size_t)t + 1];  // {row1.b,row1.c,row2.a,row2.b}
        int4 r2 = repr4[3 * (size_t)t + 2];  // {row2.c,row3.a,row3.b,row3.c}

        unsigned m0 = (1u << r0.x) | (1u << r0.y) | (1u << r0.z);
        unsigned m1 = (1u << r0.w) | (1u << r1.x) | (1u << r1.y);
        unsigned m2 = (1u << r1.z) | (1u << r1.w) | (1u << r2.x);
        unsigned m3 = (1u << r2.y) | (1u << r2.z) | (1u << r2.w);

        float t0 = (lab.x == 1) ? 1.0f : 0.0f;
        float t1 = (lab.y == 1) ? 1.0f : 0.0f;
        float t2 = (lab.z == 1) ? 1.0f : 0.0f;
        float t3 = (lab.w == 1) ? 1.0f : 0.0f;

        // flatten 7 float4 into 28 scalars (static indices only)
        float f[28];
        f[0]=L0.x;  f[1]=L0.y;  f[2]=L0.z;  f[3]=L0.w;
        f[4]=L1.x;  f[5]=L1.y;  f[6]=L1.z;  f[7]=L1.w;
        f[8]=L2.x;  f[9]=L2.y;  f[10]=L2.z; f[11]=L2.w;
        f[12]=L3.x; f[13]=L3.y; f[14]=L3.z; f[15]=L3.w;
        f[16]=L4.x; f[17]=L4.y; f[18]=L4.z; f[19]=L4.w;
        f[20]=L5.x; f[21]=L5.y; f[22]=L5.z; f[23]=L5.w;
        f[24]=L6.x; f[25]=L6.y; f[26]=L6.z; f[27]=L6.w;

        float tgt[4] = {t0, t1, t2, t3};
        unsigned mk[4] = {m0, m1, m2, m3};

        #pragma unroll
        for (int k = 0; k < 4; ++k) {
            #pragma unroll
            for (int j = 0; j < NUM_CLASSES; ++j) {
                float d = f[7 * k + j] - tgt[k];
                float v = ((mk[k] >> j) & 1u) ? fabsf(d) : fmaxf(d, 0.0f);
                acc += v;
            }
        }
    }

    // wave (64-lane) butterfly reduce
    #pragma unroll
    for (int off = 32; off > 0; off >>= 1)
        acc += __shfl_down(acc, off, 64);

    __shared__ float wave_sums[4];  // 256 threads / 64 lanes
    int lane = threadIdx.x & 63;
    int wid  = threadIdx.x >> 6;
    if (lane == 0) wave_sums[wid] = acc;
    __syncthreads();

    if (threadIdx.x == 0) {
        float s = wave_sums[0] + wave_sums[1] + wave_sums[2] + wave_sums[3];
        atomicAdd(out, s);  // device-scope by default on CDNA
    }
}

extern "C" void kernel_launch(void* const* d_in, const int* in_sizes, int n_in,
                              void* d_out, int out_size, void* d_ws, size_t ws_size,
                              hipStream_t stream) {
    const float4* logit4 = (const float4*)d_in[0];
    const int4*   label4 = (const int4*)d_in[1];
    const int4*   repr4  = (const int4*)d_in[2];
    float*        out    = (float*)d_out;

    int B = in_sizes[1];      // label is [B]
    int nchunk = B / 4;       // B = 4,000,000 -> 1,000,000 chunks

    // d_out is re-poisoned to 0xAA before every timed launch — zero it here.
    hipMemsetAsync(out, 0, sizeof(float), stream);

    int threads = 256;
    int blocks  = 2048;       // grid-stride, ~8 blocks/CU
    hinge_sum_kernel<<<blocks, threads, 0, stream>>>(logit4, label4, repr4, out, nchunk);
}